// Round 6
// baseline (396.187 us; speedup 1.0000x reference)
//
#include <hip/hip_runtime.h>
#include <math.h>

#define B_ 2
#define S_ 2048
#define D_ 1024
#define H_ 16
#define HD_ 64

typedef __bf16 bf16_t;
typedef bf16_t bf16x8 __attribute__((ext_vector_type(8)));
typedef bf16_t bf16x4v __attribute__((ext_vector_type(4)));
typedef float f32x4 __attribute__((ext_vector_type(4)));

#define GLOBAL_LOAD_LDS16(gp, lp)                                              \
    __builtin_amdgcn_global_load_lds(                                          \
        (const __attribute__((address_space(1))) void*)(gp),                   \
        (__attribute__((address_space(3))) void*)(lp), 16, 0, 0)

// ============================================================================
// fp32 -> bf16 cast. y: 0..2 = q,k,v (4M), 3..5 = W (1M), 6 = mask -> kbias
// (float -8 for valid key / -1e30 for masked; consumed by attn as MFMA C-init).
// ============================================================================
__global__ __launch_bounds__(256) void cvt_kernel(
    const float* __restrict__ q, const float* __restrict__ k,
    const float* __restrict__ v, const float* __restrict__ wq,
    const float* __restrict__ wk, const float* __restrict__ wv,
    const int* __restrict__ msk,
    bf16_t* __restrict__ qb, bf16_t* __restrict__ kb, bf16_t* __restrict__ vb,
    bf16_t* __restrict__ wqb, bf16_t* __restrict__ wkb, bf16_t* __restrict__ wvb,
    float* __restrict__ kbias)
{
    const int y = blockIdx.y;
    size_t idx = ((size_t)blockIdx.x * 256 + threadIdx.x) * 4;

    if (y == 6) {
        if (idx >= (size_t)B_ * S_) return;
        int4 mi = *(const int4*)(msk + idx);
        float4 o4;
        o4.x = mi.x ? -8.0f : -1e30f;
        o4.y = mi.y ? -8.0f : -1e30f;
        o4.z = mi.z ? -8.0f : -1e30f;
        o4.w = mi.w ? -8.0f : -1e30f;
        *(float4*)(kbias + idx) = o4;
        return;
    }

    const float* src;
    bf16_t* dst;
    size_t n;
    switch (y) {
        case 0: src = q;  dst = qb;  n = (size_t)B_ * S_ * D_; break;
        case 1: src = k;  dst = kb;  n = (size_t)B_ * S_ * D_; break;
        case 2: src = v;  dst = vb;  n = (size_t)B_ * S_ * D_; break;
        case 3: src = wq; dst = wqb; n = (size_t)D_ * D_;      break;
        case 4: src = wk; dst = wkb; n = (size_t)D_ * D_;      break;
        default: src = wv; dst = wvb; n = (size_t)D_ * D_;     break;
    }
    if (idx >= n) return;
    float4 f = *(const float4*)(src + idx);
    bf16x4v o;
    o[0] = (bf16_t)f.x; o[1] = (bf16_t)f.y;
    o[2] = (bf16_t)f.z; o[3] = (bf16_t)f.w;
    *(bf16x4v*)(dst + idx) = o;
}

// ============================================================================
// Fused projection GEMM (m97 structure). blockIdx.z selects {q,k,v}.
// z==0 (Q) epilogue folds in the 1/sqrt(HD)=0.125 score scale (exact pow2).
// ============================================================================
__global__ __launch_bounds__(256) void proj_mfma(
    const bf16_t* __restrict__ X0, const bf16_t* __restrict__ X1,
    const bf16_t* __restrict__ X2, const bf16_t* __restrict__ W0,
    const bf16_t* __restrict__ W1, const bf16_t* __restrict__ W2,
    const float* __restrict__ b0, const float* __restrict__ b1,
    const float* __restrict__ b2, bf16_t* __restrict__ o0,
    bf16_t* __restrict__ o1, bf16_t* __restrict__ o2)
{
    __shared__ __align__(16) bf16_t As[128 * 32];
    __shared__ __align__(16) bf16_t Bs[128 * 32];

    const int z = blockIdx.z;
    const bf16_t* X = (z == 0) ? X0 : (z == 1) ? X1 : X2;
    const bf16_t* W = (z == 0) ? W0 : (z == 1) ? W1 : W2;
    const float* bias = (z == 0) ? b0 : (z == 1) ? b1 : b2;
    bf16_t* out = (z == 0) ? o0 : (z == 1) ? o1 : o2;
    const float oscale = (z == 0) ? 0.125f : 1.0f;

    const int tid  = threadIdx.x;
    const int w    = tid >> 6;
    const int lane = tid & 63;
    const int L    = lane & 15;
    const int quad = lane >> 4;
    const int wr   = (w >> 1) * 64;
    const int wc   = (w & 1) * 64;
    const int row0 = blockIdx.x * 128;
    const int col0 = blockIdx.y * 128;

    const int lr = lane >> 2;
    const int lc = (lane & 3) * 8;

    f32x4 acc[4][4];
    #pragma unroll
    for (int i = 0; i < 4; ++i)
        #pragma unroll
        for (int j = 0; j < 4; ++j) {
            acc[i][j][0] = 0.f; acc[i][j][1] = 0.f;
            acc[i][j][2] = 0.f; acc[i][j][3] = 0.f;
        }

    for (int k0 = 0; k0 < D_; k0 += 32) {
        __syncthreads();
        #pragma unroll
        for (int i = 0; i < 2; ++i) {
            const int rA = i * 64 + w * 16;
            GLOBAL_LOAD_LDS16(X + (size_t)(row0 + rA + lr) * D_ + k0 + lc,
                              &As[rA * 32]);
            GLOBAL_LOAD_LDS16(W + (size_t)(col0 + rA + lr) * D_ + k0 + lc,
                              &Bs[rA * 32]);
        }
        __syncthreads();

        bf16x8 aF[4], bF[4];
        #pragma unroll
        for (int t = 0; t < 4; ++t) {
            aF[t] = *(const bf16x8*)&As[(wr + t * 16 + L) * 32 + quad * 8];
            bF[t] = *(const bf16x8*)&Bs[(wc + t * 16 + L) * 32 + quad * 8];
        }
        #pragma unroll
        for (int mt = 0; mt < 4; ++mt)
            #pragma unroll
            for (int nt = 0; nt < 4; ++nt)
                acc[mt][nt] = __builtin_amdgcn_mfma_f32_16x16x32_bf16(
                    aF[mt], bF[nt], acc[mt][nt], 0, 0, 0);
    }

    #pragma unroll
    for (int nt = 0; nt < 4; ++nt) {
        const int j  = col0 + wc + nt * 16 + L;
        const float bval = bias[j];
        const int h  = j >> 6;
        const int hd = j & 63;
        #pragma unroll
        for (int mt = 0; mt < 4; ++mt)
            #pragma unroll
            for (int r = 0; r < 4; ++r) {
                const int n = row0 + wr + mt * 16 + quad * 4 + r;
                const int b = n >> 11;
                const int s = n & (S_ - 1);
                out[((((size_t)b * H_ + h) * S_ + s) * HD_) + hd] =
                    (bf16_t)((acc[mt][nt][r] + bval) * oscale);
            }
    }
}

// ============================================================================
// V transpose: mv [B,H,S,HD] bf16 -> vt [B,H,HD,S] bf16
// ============================================================================
__global__ __launch_bounds__(256) void transpose_v(
    const bf16_t* __restrict__ mv, bf16_t* __restrict__ vt)
{
    __shared__ bf16_t tile[64][72];
    const int s0 = blockIdx.x * 64;
    const int bh = blockIdx.y;
    const int t  = threadIdx.x;

    const bf16_t* src = mv + ((size_t)bh * S_ + s0) * HD_;
    {
        int srow = t >> 2, c16 = (t & 3) * 16;
        bf16x8 a = *(const bf16x8*)(src + srow * HD_ + c16);
        bf16x8 b = *(const bf16x8*)(src + srow * HD_ + c16 + 8);
        *(bf16x8*)&tile[srow][c16]     = a;
        *(bf16x8*)&tile[srow][c16 + 8] = b;
    }
    __syncthreads();

    const int d  = t & 63;
    const int sc = (t >> 6) * 16;
    unsigned int w[8];
    #pragma unroll
    for (int j = 0; j < 8; ++j) {
        unsigned short lo = *(const unsigned short*)&tile[sc + 2*j][d];
        unsigned short hi = *(const unsigned short*)&tile[sc + 2*j + 1][d];
        w[j] = (unsigned int)lo | ((unsigned int)hi << 16);
    }
    bf16_t* dst = vt + ((size_t)bh * HD_ + d) * S_ + s0 + sc;
    uint4 u0; u0.x = w[0]; u0.y = w[1]; u0.z = w[2]; u0.w = w[3];
    uint4 u1; u1.x = w[4]; u1.y = w[5]; u1.z = w[6]; u1.w = w[7];
    ((uint4*)dst)[0] = u0;
    ((uint4*)dst)[1] = u1;
}

// ============================================================================
// MFMA flash attention, BARRIER-FREE K-loop.
// - K and Vt fragments loaded DIRECTLY from global as per-lane b128s (no LDS
//   staging, no __syncthreads). All 4 waves read the same 16KB K/V tile ->
//   L1-served. Mask bias read from precomputed kbias[] (broadcast f32x4).
// - S^T = mfma(aK, aQ) (A/B lane maps identical): lane holds 4 consecutive
//   keys for fixed q=L -> packed b64 P-writes; l is a per-lane scalar.
// - Only LDS use: 2.3KB/wave P round-trip (wave-local, in-order LDS pipe).
// - Q-tile 64, grid 1024 blocks = 4 blocks/CU (16 waves/CU) for latency
//   hiding; __launch_bounds__(256,4) caps VGPR at 128 to keep them resident.
// ============================================================================
__global__ __launch_bounds__(256, 4) void attn_kernel(
    const bf16_t* __restrict__ Q, const bf16_t* __restrict__ K,
    const bf16_t* __restrict__ Vt, const float* __restrict__ kbias,
    const int* __restrict__ mask, float* __restrict__ out)
{
    constexpr int LDP = 72;
    __shared__ bf16_t Pt[4][16 * LDP];

    const int tid  = threadIdx.x;
    const int w    = tid >> 6;
    const int lane = tid & 63;
    const int L    = lane & 15;
    const int quad = lane >> 4;
    const int h    = blockIdx.y;
    const int b    = blockIdx.z;
    const int bh   = b * H_ + h;
    const int q0   = blockIdx.x * 64;
    const int qrow = q0 + w * 16 + L;     // this lane's q (B-operand col, l acc)

    const bf16_t* kbase = K  + (size_t)bh * S_ * HD_;
    const bf16_t* vbase = Vt + (size_t)bh * HD_ * S_;
    const float*  bbase = kbias + b * S_;

    // Q fragments from global (B-operand: n=L=q, k=quad*8+j)
    const bf16_t* qp = Q + ((size_t)bh * S_ + qrow) * HD_;
    const bf16x8 aQ0 = *(const bf16x8*)(qp + quad * 8);
    const bf16x8 aQ1 = *(const bf16x8*)(qp + 32 + quad * 8);

    f32x4 o[4];
    #pragma unroll
    for (int f = 0; f < 4; ++f) { o[f][0]=0.f; o[f][1]=0.f; o[f][2]=0.f; o[f][3]=0.f; }
    float l_ = 0.f;

    bf16_t* pw = &Pt[w][0];

    for (int kt = 0; kt < S_; kt += 64) {
        // ---- QK^T: S^T = K.Q^T with bias-initialized accumulator ----
        f32x4 sc[4];
        {
            bf16x8 aK[4][2];
            #pragma unroll
            for (int f = 0; f < 4; ++f) {
                const bf16_t* kp = kbase + (size_t)(kt + f * 16 + L) * HD_;
                aK[f][0] = *(const bf16x8*)(kp + quad * 8);
                aK[f][1] = *(const bf16x8*)(kp + 32 + quad * 8);
            }
            #pragma unroll
            for (int f = 0; f < 4; ++f) {
                f32x4 z = *(const f32x4*)(bbase + kt + f * 16 + quad * 4);
                z = __builtin_amdgcn_mfma_f32_16x16x32_bf16(aK[f][0], aQ0, z, 0, 0, 0);
                z = __builtin_amdgcn_mfma_f32_16x16x32_bf16(aK[f][1], aQ1, z, 0, 0, 0);
                sc[f] = z;
            }
        }

        // ---- V fragments (issued now; consumed after exp) ----
        bf16x8 bV[4][2];
        #pragma unroll
        for (int f = 0; f < 4; ++f) {
            const bf16_t* vp = vbase + (size_t)(f * 16 + L) * S_ + kt;
            bV[f][0] = *(const bf16x8*)(vp + quad * 8);
            bV[f][1] = *(const bf16x8*)(vp + 32 + quad * 8);
        }

        // ---- p = exp(s), l accumulate, packed P staging (wave-local) ----
        #pragma unroll
        for (int f = 0; f < 4; ++f) {
            float e0 = __expf(sc[f][0]);
            float e1 = __expf(sc[f][1]);
            float e2 = __expf(sc[f][2]);
            float e3 = __expf(sc[f][3]);
            l_ += (e0 + e1) + (e2 + e3);
            bf16x4v p4;
            p4[0] = (bf16_t)e0; p4[1] = (bf16_t)e1;
            p4[2] = (bf16_t)e2; p4[3] = (bf16_t)e3;
            *(bf16x4v*)&pw[L * LDP + f * 16 + quad * 4] = p4;
        }

        // ---- P fragments (A-operand: m=L=q, k=quad*8+j=key) ----
        bf16x8 aP0 = *(const bf16x8*)&pw[L * LDP + quad * 8];
        bf16x8 aP1 = *(const bf16x8*)&pw[L * LDP + 32 + quad * 8];

        // ---- PV ----
        #pragma unroll
        for (int f = 0; f < 4; ++f) {
            o[f] = __builtin_amdgcn_mfma_f32_16x16x32_bf16(aP0, bV[f][0], o[f], 0, 0, 0);
            o[f] = __builtin_amdgcn_mfma_f32_16x16x32_bf16(aP1, bV[f][1], o[f], 0, 0, 0);
        }
    }

    // ---- l: full sum lives per (L, any quad) after xor-reduce ----
    float t = l_;
    t += __shfl_xor(t, 16);
    t += __shfl_xor(t, 32);
    int qv = mask[b * S_ + qrow];
    float linv = (qv && t > 0.f) ? (1.0f / t) : 0.0f;

    // o rows are q = quad*4+r -> fetch that row's inv from lane L'=quad*4+r
    float inv[4];
    #pragma unroll
    for (int r = 0; r < 4; ++r)
        inv[r] = __shfl(linv, quad * 4 + r);

    float* obase = out + ((size_t)b * S_ + q0 + w * 16 + quad * 4) * D_ + h * HD_;
    #pragma unroll
    for (int f = 0; f < 4; ++f)
        #pragma unroll
        for (int r = 0; r < 4; ++r)
            obase[r * D_ + f * 16 + L] = o[f][r] * inv[r];
}

// ============================================================================
extern "C" void kernel_launch(void* const* d_in, const int* in_sizes, int n_in,
                              void* d_out, int out_size, void* d_ws, size_t ws_size,
                              hipStream_t stream)
{
    const float* q    = (const float*)d_in[0];
    const float* k    = (const float*)d_in[1];
    const float* v    = (const float*)d_in[2];
    const int*   mask = (const int*)d_in[3];
    const float* Wq   = (const float*)d_in[4];
    const float* bq   = (const float*)d_in[5];
    const float* Wk   = (const float*)d_in[6];
    const float* bk   = (const float*)d_in[7];
    const float* Wv   = (const float*)d_in[8];
    const float* bv   = (const float*)d_in[9];
    float* out = (float*)d_out;

    const size_t PE = (size_t)B_ * S_ * D_;           // 4,194,304 per tensor
    const size_t WE = (size_t)D_ * D_;                // 1,048,576 per weight

    bf16_t* qb    = (bf16_t*)d_ws;
    bf16_t* kb    = qb + PE;
    bf16_t* vb    = kb + PE;
    bf16_t* wqb   = vb + PE;
    bf16_t* wkb   = wqb + WE;
    bf16_t* wvb   = wkb + WE;
    bf16_t* mq    = wvb + WE;
    bf16_t* mk    = mq + PE;
    bf16_t* mv    = mk + PE;
    bf16_t* vt    = mv + PE;
    float*  kbias = (float*)(vt + PE);

    dim3 cgrid(PE / (256 * 4), 7);
    cvt_kernel<<<cgrid, 256, 0, stream>>>(q, k, v, Wq, Wk, Wv, mask,
                                          qb, kb, vb, wqb, wkb, wvb, kbias);

    dim3 pgrid(4096 / 128, 1024 / 128, 3);
    proj_mfma<<<pgrid, 256, 0, stream>>>(qb, kb, vb, wqb, wkb, wvb,
                                         bq, bk, bv, mq, mk, mv);

    dim3 tgrid(S_ / 64, B_ * H_);
    transpose_v<<<tgrid, 256, 0, stream>>>(mv, vt);

    dim3 agrid(S_ / 64, H_, B_);
    attn_kernel<<<agrid, 256, 0, stream>>>(mq, mk, vt, kbias, mask, out);
}

// Round 7
// 211.584 us; speedup vs baseline: 1.8725x; 1.8725x over previous
//
#include <hip/hip_runtime.h>
#include <math.h>

#define B_ 2
#define S_ 2048
#define D_ 1024
#define H_ 16
#define HD_ 64

typedef __bf16 bf16_t;
typedef bf16_t bf16x8 __attribute__((ext_vector_type(8)));
typedef bf16_t bf16x4v __attribute__((ext_vector_type(4)));
typedef float f32x4 __attribute__((ext_vector_type(4)));

#define GLOBAL_LOAD_LDS16(gp, lp)                                              \
    __builtin_amdgcn_global_load_lds(                                          \
        (const __attribute__((address_space(1))) void*)(gp),                   \
        (__attribute__((address_space(3))) void*)(lp), 16, 0, 0)

// ============================================================================
// fp32 -> bf16 cast. y: 0..2 = q,k,v (4M), 3..5 = W (1M), 6 = mask -> kbias
// (float -8 valid / -1e30 masked; consumed by attn as MFMA C-init).
// ============================================================================
__global__ __launch_bounds__(256) void cvt_kernel(
    const float* __restrict__ q, const float* __restrict__ k,
    const float* __restrict__ v, const float* __restrict__ wq,
    const float* __restrict__ wk, const float* __restrict__ wv,
    const int* __restrict__ msk,
    bf16_t* __restrict__ qb, bf16_t* __restrict__ kb, bf16_t* __restrict__ vb,
    bf16_t* __restrict__ wqb, bf16_t* __restrict__ wkb, bf16_t* __restrict__ wvb,
    float* __restrict__ kbias)
{
    const int y = blockIdx.y;
    size_t idx = ((size_t)blockIdx.x * 256 + threadIdx.x) * 4;

    if (y == 6) {
        if (idx >= (size_t)B_ * S_) return;
        int4 mi = *(const int4*)(msk + idx);
        float4 o4;
        o4.x = mi.x ? -8.0f : -1e30f;
        o4.y = mi.y ? -8.0f : -1e30f;
        o4.z = mi.z ? -8.0f : -1e30f;
        o4.w = mi.w ? -8.0f : -1e30f;
        *(float4*)(kbias + idx) = o4;
        return;
    }

    const float* src;
    bf16_t* dst;
    size_t n;
    switch (y) {
        case 0: src = q;  dst = qb;  n = (size_t)B_ * S_ * D_; break;
        case 1: src = k;  dst = kb;  n = (size_t)B_ * S_ * D_; break;
        case 2: src = v;  dst = vb;  n = (size_t)B_ * S_ * D_; break;
        case 3: src = wq; dst = wqb; n = (size_t)D_ * D_;      break;
        case 4: src = wk; dst = wkb; n = (size_t)D_ * D_;      break;
        default: src = wv; dst = wvb; n = (size_t)D_ * D_;     break;
    }
    if (idx >= n) return;
    float4 f = *(const float4*)(src + idx);
    bf16x4v o;
    o[0] = (bf16_t)f.x; o[1] = (bf16_t)f.y;
    o[2] = (bf16_t)f.z; o[3] = (bf16_t)f.w;
    *(bf16x4v*)(dst + idx) = o;
}

// ============================================================================
// Fused projection GEMM (m97 structure). blockIdx.z selects {q,k,v}.
// z==0 (Q) epilogue folds in the 1/sqrt(HD)=0.125 score scale (exact pow2).
// ============================================================================
__global__ __launch_bounds__(256) void proj_mfma(
    const bf16_t* __restrict__ X0, const bf16_t* __restrict__ X1,
    const bf16_t* __restrict__ X2, const bf16_t* __restrict__ W0,
    const bf16_t* __restrict__ W1, const bf16_t* __restrict__ W2,
    const float* __restrict__ b0, const float* __restrict__ b1,
    const float* __restrict__ b2, bf16_t* __restrict__ o0,
    bf16_t* __restrict__ o1, bf16_t* __restrict__ o2)
{
    __shared__ __align__(16) bf16_t As[128 * 32];
    __shared__ __align__(16) bf16_t Bs[128 * 32];

    const int z = blockIdx.z;
    const bf16_t* X = (z == 0) ? X0 : (z == 1) ? X1 : X2;
    const bf16_t* W = (z == 0) ? W0 : (z == 1) ? W1 : W2;
    const float* bias = (z == 0) ? b0 : (z == 1) ? b1 : b2;
    bf16_t* out = (z == 0) ? o0 : (z == 1) ? o1 : o2;
    const float oscale = (z == 0) ? 0.125f : 1.0f;

    const int tid  = threadIdx.x;
    const int w    = tid >> 6;
    const int lane = tid & 63;
    const int L    = lane & 15;
    const int quad = lane >> 4;
    const int wr   = (w >> 1) * 64;
    const int wc   = (w & 1) * 64;
    const int row0 = blockIdx.x * 128;
    const int col0 = blockIdx.y * 128;

    const int lr = lane >> 2;
    const int lc = (lane & 3) * 8;

    f32x4 acc[4][4];
    #pragma unroll
    for (int i = 0; i < 4; ++i)
        #pragma unroll
        for (int j = 0; j < 4; ++j) {
            acc[i][j][0] = 0.f; acc[i][j][1] = 0.f;
            acc[i][j][2] = 0.f; acc[i][j][3] = 0.f;
        }

    for (int k0 = 0; k0 < D_; k0 += 32) {
        __syncthreads();
        #pragma unroll
        for (int i = 0; i < 2; ++i) {
            const int rA = i * 64 + w * 16;
            GLOBAL_LOAD_LDS16(X + (size_t)(row0 + rA + lr) * D_ + k0 + lc,
                              &As[rA * 32]);
            GLOBAL_LOAD_LDS16(W + (size_t)(col0 + rA + lr) * D_ + k0 + lc,
                              &Bs[rA * 32]);
        }
        __syncthreads();

        bf16x8 aF[4], bF[4];
        #pragma unroll
        for (int t = 0; t < 4; ++t) {
            aF[t] = *(const bf16x8*)&As[(wr + t * 16 + L) * 32 + quad * 8];
            bF[t] = *(const bf16x8*)&Bs[(wc + t * 16 + L) * 32 + quad * 8];
        }
        #pragma unroll
        for (int mt = 0; mt < 4; ++mt)
            #pragma unroll
            for (int nt = 0; nt < 4; ++nt)
                acc[mt][nt] = __builtin_amdgcn_mfma_f32_16x16x32_bf16(
                    aF[mt], bF[nt], acc[mt][nt], 0, 0, 0);
    }

    #pragma unroll
    for (int nt = 0; nt < 4; ++nt) {
        const int j  = col0 + wc + nt * 16 + L;
        const float bval = bias[j];
        const int h  = j >> 6;
        const int hd = j & 63;
        #pragma unroll
        for (int mt = 0; mt < 4; ++mt)
            #pragma unroll
            for (int r = 0; r < 4; ++r) {
                const int n = row0 + wr + mt * 16 + quad * 4 + r;
                const int b = n >> 11;
                const int s = n & (S_ - 1);
                out[((((size_t)b * H_ + h) * S_ + s) * HD_) + hd] =
                    (bf16_t)((acc[mt][nt][r] + bval) * oscale);
            }
    }
}

// ============================================================================
// V transpose: mv [B,H,S,HD] bf16 -> vt [B,H,HD,S] bf16
// ============================================================================
__global__ __launch_bounds__(256) void transpose_v(
    const bf16_t* __restrict__ mv, bf16_t* __restrict__ vt)
{
    __shared__ bf16_t tile[64][72];
    const int s0 = blockIdx.x * 64;
    const int bh = blockIdx.y;
    const int t  = threadIdx.x;

    const bf16_t* src = mv + ((size_t)bh * S_ + s0) * HD_;
    {
        int srow = t >> 2, c16 = (t & 3) * 16;
        bf16x8 a = *(const bf16x8*)(src + srow * HD_ + c16);
        bf16x8 b = *(const bf16x8*)(src + srow * HD_ + c16 + 8);
        *(bf16x8*)&tile[srow][c16]     = a;
        *(bf16x8*)&tile[srow][c16 + 8] = b;
    }
    __syncthreads();

    const int d  = t & 63;
    const int sc = (t >> 6) * 16;
    unsigned int w[8];
    #pragma unroll
    for (int j = 0; j < 8; ++j) {
        unsigned short lo = *(const unsigned short*)&tile[sc + 2*j][d];
        unsigned short hi = *(const unsigned short*)&tile[sc + 2*j + 1][d];
        w[j] = (unsigned int)lo | ((unsigned int)hi << 16);
    }
    bf16_t* dst = vt + ((size_t)bh * HD_ + d) * S_ + s0 + sc;
    uint4 u0; u0.x = w[0]; u0.y = w[1]; u0.z = w[2]; u0.w = w[3];
    uint4 u1; u1.x = w[4]; u1.y = w[5]; u1.z = w[6]; u1.w = w[7];
    ((uint4*)dst)[0] = u0;
    ((uint4*)dst)[1] = u1;
}

// ============================================================================
// MFMA flash attention (R5 structure + register-prefetch staging).
// - S^T = mfma(aK, aQ): lane holds 4 consecutive keys for fixed q=L ->
//   packed b64 P-writes; l is a per-lane scalar (reduced once at end).
// - Mask folded into MFMA C-init via precomputed kbias (-8 / -1e30).
// - REGISTER PREFETCH: K/V/bias for tile kt+64 are loaded into registers
//   immediately after the staging barrier and written to LDS at the NEXT
//   iteration -> global latency hides behind a full compute phase. The
//   compute phase contains zero global loads, so nothing drains vmcnt early.
// - Q-tile 128 (2 qb sub-blocks/wave, aK/bV shared across qb), key-tile 64.
// ============================================================================
__global__ __launch_bounds__(256) void attn_kernel(
    const bf16_t* __restrict__ Q, const bf16_t* __restrict__ K,
    const bf16_t* __restrict__ Vt, const float* __restrict__ kbias,
    const int* __restrict__ mask, float* __restrict__ out)
{
    constexpr int LD = 72;
    __shared__ bf16_t Ks[64 * LD];
    __shared__ bf16_t Vs[64 * LD];        // [d][key]
    __shared__ bf16_t Pt[4][32 * LD];     // per-wave P, [q(32)][key(64)]

    const int tid  = threadIdx.x;
    const int w    = tid >> 6;
    const int lane = tid & 63;
    const int L    = lane & 15;
    const int quad = lane >> 4;
    const int h    = blockIdx.y;
    const int b    = blockIdx.z;
    const int bh   = b * H_ + h;
    const int q0   = blockIdx.x * 128;

    const bf16_t* kbase = K  + (size_t)bh * S_ * HD_;
    const bf16_t* vbase = Vt + (size_t)bh * HD_ * S_;
    const float*  bbase = kbias + b * S_;
    const int*    mrow  = mask + b * S_;

    // Staging coordinates: 256 threads cover a 64x64 bf16 tile as 2 chunks
    const int sr = tid >> 3;            // 0..31
    const int sc2 = (tid & 7) * 8;      // 0..56

    // Q fragments straight from global (one-time)
    bf16x8 aQ[2][2];
    #pragma unroll
    for (int qb = 0; qb < 2; ++qb) {
        const bf16_t* qp = Q + ((size_t)bh * S_ + q0 + w * 32 + qb * 16 + L) * HD_;
        aQ[qb][0] = *(const bf16x8*)(qp + quad * 8);
        aQ[qb][1] = *(const bf16x8*)(qp + 32 + quad * 8);
    }

    f32x4 o[2][4];
    #pragma unroll
    for (int qb = 0; qb < 2; ++qb)
        #pragma unroll
        for (int f = 0; f < 4; ++f) {
            o[qb][f][0]=0.f; o[qb][f][1]=0.f; o[qb][f][2]=0.f; o[qb][f][3]=0.f;
        }
    float l_[2] = {0.f, 0.f};

    // ---- prefetch registers (tile kt) ----
    bf16x8 kr0, kr1, vr0, vr1;
    f32x4  bias_n[4];
    {
        kr0 = *(const bf16x8*)(kbase + (size_t)sr * HD_ + sc2);
        kr1 = *(const bf16x8*)(kbase + (size_t)(sr + 32) * HD_ + sc2);
        vr0 = *(const bf16x8*)(vbase + (size_t)sr * S_ + sc2);
        vr1 = *(const bf16x8*)(vbase + (size_t)(sr + 32) * S_ + sc2);
        #pragma unroll
        for (int f = 0; f < 4; ++f)
            bias_n[f] = *(const f32x4*)(bbase + f * 16 + quad * 4);
    }

    for (int kt = 0; kt < S_; kt += 64) {
        __syncthreads();    // previous tile's LDS frag reads complete
        *(bf16x8*)&Ks[sr * LD + sc2]        = kr0;
        *(bf16x8*)&Ks[(sr + 32) * LD + sc2] = kr1;
        *(bf16x8*)&Vs[sr * LD + sc2]        = vr0;
        *(bf16x8*)&Vs[(sr + 32) * LD + sc2] = vr1;
        f32x4 bias_c[4];
        #pragma unroll
        for (int f = 0; f < 4; ++f) bias_c[f] = bias_n[f];
        __syncthreads();    // staging visible to all waves

        // ---- issue next tile's prefetch (consumed next iteration) ----
        if (kt + 64 < S_) {
            const int kn = kt + 64;
            kr0 = *(const bf16x8*)(kbase + (size_t)(kn + sr) * HD_ + sc2);
            kr1 = *(const bf16x8*)(kbase + (size_t)(kn + sr + 32) * HD_ + sc2);
            vr0 = *(const bf16x8*)(vbase + (size_t)sr * S_ + kn + sc2);
            vr1 = *(const bf16x8*)(vbase + (size_t)(sr + 32) * S_ + kn + sc2);
            #pragma unroll
            for (int f = 0; f < 4; ++f)
                bias_n[f] = *(const f32x4*)(bbase + kn + f * 16 + quad * 4);
        }

        // ---- K fragments ----
        bf16x8 aK[4][2];
        #pragma unroll
        for (int f = 0; f < 4; ++f) {
            aK[f][0] = *(const bf16x8*)&Ks[(f * 16 + L) * LD + quad * 8];
            aK[f][1] = *(const bf16x8*)&Ks[(f * 16 + L) * LD + 32 + quad * 8];
        }

        // ---- S^T = K.Q^T, p = exp(s), packed P staging ----
        bf16_t* pw = &Pt[w][0];
        #pragma unroll
        for (int qb = 0; qb < 2; ++qb) {
            #pragma unroll
            for (int f = 0; f < 4; ++f) {
                f32x4 z = bias_c[f];   // rows = keys f*16+quad*4+r
                z = __builtin_amdgcn_mfma_f32_16x16x32_bf16(aK[f][0], aQ[qb][0], z, 0, 0, 0);
                z = __builtin_amdgcn_mfma_f32_16x16x32_bf16(aK[f][1], aQ[qb][1], z, 0, 0, 0);
                float e0 = __expf(z[0]);
                float e1 = __expf(z[1]);
                float e2 = __expf(z[2]);
                float e3 = __expf(z[3]);
                l_[qb] += (e0 + e1) + (e2 + e3);
                bf16x4v p4;
                p4[0] = (bf16_t)e0; p4[1] = (bf16_t)e1;
                p4[2] = (bf16_t)e2; p4[3] = (bf16_t)e3;
                *(bf16x4v*)&pw[(qb * 16 + L) * LD + f * 16 + quad * 4] = p4;
            }
        }

        // ---- P fragments ----
        bf16x8 aP[2][2];
        #pragma unroll
        for (int qb = 0; qb < 2; ++qb) {
            aP[qb][0] = *(const bf16x8*)&pw[(qb * 16 + L) * LD + quad * 8];
            aP[qb][1] = *(const bf16x8*)&pw[(qb * 16 + L) * LD + 32 + quad * 8];
        }

        // ---- PV: bV read once per f, shared across qb ----
        #pragma unroll
        for (int f = 0; f < 4; ++f) {
            bf16x8 bV0 = *(const bf16x8*)&Vs[(f * 16 + L) * LD + quad * 8];
            bf16x8 bV1 = *(const bf16x8*)&Vs[(f * 16 + L) * LD + 32 + quad * 8];
            #pragma unroll
            for (int qb = 0; qb < 2; ++qb) {
                o[qb][f] = __builtin_amdgcn_mfma_f32_16x16x32_bf16(aP[qb][0], bV0, o[qb][f], 0, 0, 0);
                o[qb][f] = __builtin_amdgcn_mfma_f32_16x16x32_bf16(aP[qb][1], bV1, o[qb][f], 0, 0, 0);
            }
        }
    }

    // ---- l: reduce across quads, invert, distribute ----
    #pragma unroll
    for (int qb = 0; qb < 2; ++qb) {
        float t = l_[qb];
        t += __shfl_xor(t, 16);
        t += __shfl_xor(t, 32);
        int qv = mrow[q0 + w * 32 + qb * 16 + L];
        l_[qb] = (qv && t > 0.f) ? (1.0f / t) : 0.0f;
    }

    #pragma unroll
    for (int qb = 0; qb < 2; ++qb) {
        float inv[4];
        #pragma unroll
        for (int r = 0; r < 4; ++r)
            inv[r] = __shfl(l_[qb], quad * 4 + r);
        float* obase = out + ((size_t)b * S_ + q0 + w * 32 + qb * 16 + quad * 4) * D_ + h * HD_;
        #pragma unroll
        for (int f = 0; f < 4; ++f)
            #pragma unroll
            for (int r = 0; r < 4; ++r)
                obase[r * D_ + f * 16 + L] = o[qb][f][r] * inv[r];
    }
}

// ============================================================================
extern "C" void kernel_launch(void* const* d_in, const int* in_sizes, int n_in,
                              void* d_out, int out_size, void* d_ws, size_t ws_size,
                              hipStream_t stream)
{
    const float* q    = (const float*)d_in[0];
    const float* k    = (const float*)d_in[1];
    const float* v    = (const float*)d_in[2];
    const int*   mask = (const int*)d_in[3];
    const float* Wq   = (const float*)d_in[4];
    const float* bq   = (const float*)d_in[5];
    const float* Wk   = (const float*)d_in[6];
    const float* bk   = (const float*)d_in[7];
    const float* Wv   = (const float*)d_in[8];
    const float* bv   = (const float*)d_in[9];
    float* out = (float*)d_out;

    const size_t PE = (size_t)B_ * S_ * D_;           // 4,194,304 per tensor
    const size_t WE = (size_t)D_ * D_;                // 1,048,576 per weight

    bf16_t* qb    = (bf16_t*)d_ws;
    bf16_t* kb    = qb + PE;
    bf16_t* vb    = kb + PE;
    bf16_t* wqb   = vb + PE;
    bf16_t* wkb   = wqb + WE;
    bf16_t* wvb   = wkb + WE;
    bf16_t* mq    = wvb + WE;
    bf16_t* mk    = mq + PE;
    bf16_t* mv    = mk + PE;
    bf16_t* vt    = mv + PE;
    float*  kbias = (float*)(vt + PE);

    dim3 cgrid(PE / (256 * 4), 7);
    cvt_kernel<<<cgrid, 256, 0, stream>>>(q, k, v, Wq, Wk, Wv, mask,
                                          qb, kb, vb, wqb, wkb, wvb, kbias);

    dim3 pgrid(4096 / 128, 1024 / 128, 3);
    proj_mfma<<<pgrid, 256, 0, stream>>>(qb, kb, vb, wqb, wkb, wvb,
                                         bq, bk, bv, mq, mk, mv);

    dim3 tgrid(S_ / 64, B_ * H_);
    transpose_v<<<tgrid, 256, 0, stream>>>(mv, vt);

    dim3 agrid(S_ / 128, H_, B_);
    attn_kernel<<<agrid, 256, 0, stream>>>(mq, mk, vt, kbias, mask, out);
}